// Round 1
// baseline (4912.115 us; speedup 1.0000x reference)
//
#include <hip/hip_runtime.h>
#include <hip/hip_bf16.h>

typedef _Float16 f16;
typedef _Float16 f16x8 __attribute__((ext_vector_type(8)));
typedef _Float16 f16x4 __attribute__((ext_vector_type(4)));
typedef float f32x4 __attribute__((ext_vector_type(4)));

// ---------------- ws layout (bytes) ----------------
// P:   4096*900*4 = 14745600            at 0
// w1t: 512*256*2  = 262144              at 14745600
// w2t: 512*512*2  = 524288              at 15007744
#define P_OFF   0
#define W1T_OFF 14745600
#define W2T_OFF 15007744

// ---------------- k_prep: transpose + f32->f16 weights ----------------
__global__ __launch_bounds__(256) void k_prep(const float* __restrict__ W1,
                                              const float* __restrict__ W2,
                                              f16* __restrict__ w1t,
                                              f16* __restrict__ w2t) {
    long id = (long)blockIdx.x * 256 + threadIdx.x;   // 0 .. 393215
    if (id < 131072) {
        int f = (int)(id >> 8), k = (int)(id & 255);
        w1t[id] = (f16)W1[k * 512 + f];               // w1t[f][k], k=0..255
    } else {
        long i = id - 131072;
        int f = (int)(i >> 9), k = (int)(i & 511);
        w2t[i] = (f16)W2[k * 512 + f];                // w2t[f][k], k=0..511
    }
}

// ---------------- k_prop: per-batch P = alpha*sum 0.9^k S^k + 0.9^10 S^10 ----
__global__ __launch_bounds__(256) void k_prop(const float* __restrict__ graph,
                                              float* __restrict__ P) {
    __shared__ float Mt[900];
    __shared__ float Sm[900];
    __shared__ float Q[900];
    __shared__ float T[900];
    __shared__ float R[900];
    __shared__ float dinv[30];
    const int tid = threadIdx.x;
    const int b = blockIdx.x;
    const float* g = graph + (long)b * 4500;

    for (int e = tid; e < 900; e += 256) {
        float s = g[e];
        s += g[900 + e]; s += g[1800 + e]; s += g[2700 + e]; s += g[3600 + e];
        int i = e / 30, j = e - i * 30;
        float m = (s != 0.0f) ? 1.0f : 0.0f;          // mean!=0 <=> sum!=0
        Mt[e] = m + ((i == j) ? 1.0f : 0.0f);
    }
    __syncthreads();
    if (tid < 30) {
        float d = 0.f;
        for (int i = 0; i < 30; ++i) d += Mt[i * 30 + tid];   // column sum
        dinv[tid] = 1.0f / sqrtf(d);
    }
    __syncthreads();
    for (int e = tid; e < 900; e += 256) {
        int i = e / 30, j = e - i * 30;
        float s = dinv[i] * Mt[j * 30 + i] * dinv[j];         // S = Dinv * Mt^T * Dinv
        Sm[e] = s;
        Q[e] = s;                                              // Q = S^1
        R[e] = 0.1f * ((i == j) ? 1.0f : 0.0f);                // alpha * I
    }
    __syncthreads();
    float c = 0.1f, g9 = 1.0f;
    for (int k = 1; k <= 9; ++k) {
        c *= 0.9f; g9 *= 0.9f;
        for (int e = tid; e < 900; e += 256) {
            int i = e / 30, j = e - i * 30;
            R[e] += c * Q[e];
            float acc = 0.f;
            #pragma unroll
            for (int t = 0; t < 30; ++t) acc += Sm[i * 30 + t] * Q[t * 30 + j];
            T[e] = acc;
        }
        __syncthreads();
        for (int e = tid; e < 900; e += 256) Q[e] = T[e];
        __syncthreads();
    }
    const float cf = g9 * 0.9f;                                // 0.9^10
    for (int e = tid; e < 900; e += 256)
        P[(long)b * 900 + e] = R[e] + cf * Q[e];
}

// ---------------- k_main: fused GEMM1+GEMM2+P-apply+readout ----------------
// block = 2 batches (60 rows, padded to 64), 512 threads = 8 waves (1M x 8N).
#define SMEM_BYTES 114432
#define XL_OFF   0        // [64][512] f16, 65536 B (x, then reused for u)
#define BS_OFF   65536    // [512][32] f16, 32768 B
#define AS_OFF   98304    // [64][32]  f16, 4096 B
#define PL_OFF   102400   // [2][900]  f32, 7200 B
#define B1L_OFF  109600   // [512] f32, 2048 B
#define RED_OFF  111648   // [8][64] f32, 2048 B
#define VL_OFF   113696   // [64] f32
#define ZL_OFF   113952   // [64] f32

__global__ __launch_bounds__(512, 2) void k_main(
    const float* __restrict__ real, const f16* __restrict__ w1t,
    const f16* __restrict__ w2t, const float* __restrict__ b1,
    const float* __restrict__ b2, const float* __restrict__ wl,
    const float* __restrict__ bl, const float* __restrict__ wc,
    const float* __restrict__ bc, const float* __restrict__ Pws,
    float* __restrict__ out) {
    extern __shared__ char smem[];
    f16*   xl  = (f16*)(smem + XL_OFF);
    f16*   Bs  = (f16*)(smem + BS_OFF);
    f16*   As  = (f16*)(smem + AS_OFF);
    float* Pl  = (float*)(smem + PL_OFF);
    float* b1l = (float*)(smem + B1L_OFF);
    float* red = (float*)(smem + RED_OFF);
    float* vl  = (float*)(smem + VL_OFF);
    float* zl  = (float*)(smem + ZL_OFF);

    const int tid  = threadIdx.x;
    const int lane = tid & 63;
    const int wv   = tid >> 6;          // wave 0..7, owns cols wv*64..+63
    const int blk  = blockIdx.x;        // 0..2047
    const long r0  = (long)blk * 60;    // row base in flattened [122880]

    b1l[tid] = b1[tid];
    for (int e = tid; e < 1800; e += 512) Pl[e] = Pws[(long)blk * 1800 + e];

    const int lr = lane & 15;
    const int kb = (lane >> 4) * 16;    // byte offset of k-slice in 64B row
    const int kq = (lane >> 4) * 8;     // element offset of k-slice

    f32x4 acc[4][4];
    #pragma unroll
    for (int mi = 0; mi < 4; ++mi)
        #pragma unroll
        for (int ni = 0; ni < 4; ++ni) { f32x4 z = {0.f,0.f,0.f,0.f}; acc[mi][ni] = z; }

    // ================= GEMM1: x = relu(real @ W1 + b1), K=256 =================
    for (int kc = 0; kc < 8; ++kc) {
        const int k0 = kc * 32;
        __syncthreads();
        {   // stage A (60x32 from f32, rows 60..63 zero), swizzled
            const int r = tid >> 3, c0 = (tid & 7) * 4;
            float4 v = {0.f, 0.f, 0.f, 0.f};
            if (r < 60) v = *reinterpret_cast<const float4*>(real + (r0 + r) * 256 + k0 + c0);
            f16x4 h; h[0] = (f16)v.x; h[1] = (f16)v.y; h[2] = (f16)v.z; h[3] = (f16)v.w;
            *reinterpret_cast<f16x4*>((char*)As + ((r * 64 + c0 * 2) ^ ((r & 7) << 4))) = h;
        }
        #pragma unroll
        for (int ch = 0; ch < 4; ++ch) {   // stage B [512][32] from w1t, swizzled
            const int n = ch * 128 + (tid >> 2);
            const int kk = (tid & 3) * 8;
            f16x8 bv = *reinterpret_cast<const f16x8*>(w1t + n * 256 + k0 + kk);
            *reinterpret_cast<f16x8*>((char*)Bs + ((n * 64 + kk * 2) ^ ((n & 7) << 4))) = bv;
        }
        __syncthreads();
        f16x8 af[4], bf[4];
        #pragma unroll
        for (int mi = 0; mi < 4; ++mi) {
            const int row = mi * 16 + lr;
            af[mi] = *reinterpret_cast<const f16x8*>((char*)As + ((row * 64 + kb) ^ ((row & 7) << 4)));
        }
        #pragma unroll
        for (int ni = 0; ni < 4; ++ni) {
            const int n = wv * 64 + ni * 16 + lr;
            bf[ni] = *reinterpret_cast<const f16x8*>((char*)Bs + ((n * 64 + kb) ^ ((n & 7) << 4)));
        }
        #pragma unroll
        for (int mi = 0; mi < 4; ++mi)
            #pragma unroll
            for (int ni = 0; ni < 4; ++ni)
                acc[mi][ni] = __builtin_amdgcn_mfma_f32_16x16x32_f16(af[mi], bf[ni], acc[mi][ni], 0, 0, 0);
    }
    __syncthreads();
    // epilogue1: x = relu(acc + b1) -> xl (f16, swizzled (row&7)<<4)
    #pragma unroll
    for (int mi = 0; mi < 4; ++mi)
        #pragma unroll
        for (int ni = 0; ni < 4; ++ni)
            #pragma unroll
            for (int j = 0; j < 4; ++j) {
                const int row = mi * 16 + (lane >> 4) * 4 + j;
                const int col = wv * 64 + ni * 16 + lr;
                float xv = fmaxf(acc[mi][ni][j] + b1l[col], 0.f);
                *reinterpret_cast<f16*>((char*)xl + ((row * 1024 + col * 2) ^ ((row & 7) << 4))) = (f16)xv;
            }
    #pragma unroll
    for (int mi = 0; mi < 4; ++mi)
        #pragma unroll
        for (int ni = 0; ni < 4; ++ni) { f32x4 z = {0.f,0.f,0.f,0.f}; acc[mi][ni] = z; }
    __syncthreads();

    // ================= GEMM2: u = x @ W2, K=512 (A from xl) =================
    for (int kc = 0; kc < 16; ++kc) {
        const int k0 = kc * 32;
        if (kc) __syncthreads();
        #pragma unroll
        for (int ch = 0; ch < 4; ++ch) {
            const int n = ch * 128 + (tid >> 2);
            const int kk = (tid & 3) * 8;
            f16x8 bv = *reinterpret_cast<const f16x8*>(w2t + n * 512 + k0 + kk);
            *reinterpret_cast<f16x8*>((char*)Bs + ((n * 64 + kk * 2) ^ ((n & 7) << 4))) = bv;
        }
        __syncthreads();
        f16x8 af[4], bf[4];
        #pragma unroll
        for (int mi = 0; mi < 4; ++mi) {
            const int row = mi * 16 + lr;
            af[mi] = *reinterpret_cast<const f16x8*>((char*)xl + ((row * 1024 + (k0 + kq) * 2) ^ ((row & 7) << 4)));
        }
        #pragma unroll
        for (int ni = 0; ni < 4; ++ni) {
            const int n = wv * 64 + ni * 16 + lr;
            bf[ni] = *reinterpret_cast<const f16x8*>((char*)Bs + ((n * 64 + kb) ^ ((n & 7) << 4)));
        }
        #pragma unroll
        for (int mi = 0; mi < 4; ++mi)
            #pragma unroll
            for (int ni = 0; ni < 4; ++ni)
                acc[mi][ni] = __builtin_amdgcn_mfma_f32_16x16x32_f16(af[mi], bf[ni], acc[mi][ni], 0, 0, 0);
    }
    __syncthreads();
    // u -> xl (overwrite x; swizzle (row&3)<<5 chosen for conflict-free column reads)
    #pragma unroll
    for (int mi = 0; mi < 4; ++mi)
        #pragma unroll
        for (int ni = 0; ni < 4; ++ni)
            #pragma unroll
            for (int j = 0; j < 4; ++j) {
                const int row = mi * 16 + (lane >> 4) * 4 + j;
                const int col = wv * 64 + ni * 16 + lr;
                *reinterpret_cast<f16*>((char*)xl + ((row * 1024 + col * 2) ^ ((row & 3) << 5))) = (f16)acc[mi][ni][j];
            }
    __syncthreads();

    // ================= phase 5: y=relu(P@u+b2); v=y@Wl; z=relu(P@v+bl); out ====
    float vpart[2][30];
    #pragma unroll
    for (int bb = 0; bb < 2; ++bb)
        #pragma unroll
        for (int n = 0; n < 30; ++n) vpart[bb][n] = 0.f;
    const float b2f = b2[tid];
    const float wlf = wl[tid];
    #pragma unroll
    for (int bb = 0; bb < 2; ++bb) {
        float uv[30];
        #pragma unroll
        for (int j = 0; j < 30; ++j) {
            const int row = bb * 30 + j;
            uv[j] = (float)*reinterpret_cast<const f16*>(
                (char*)xl + ((row * 1024 + tid * 2) ^ ((row & 3) << 5)));
        }
        #pragma unroll
        for (int n = 0; n < 30; ++n) {
            float y = b2f;
            const float* Pr = Pl + bb * 900 + n * 30;
            #pragma unroll
            for (int j = 0; j < 30; ++j) y = fmaf(Pr[j], uv[j], y);
            y = fmaxf(y, 0.f);
            vpart[bb][n] = fmaf(y, wlf, vpart[bb][n]);
        }
    }
    // reduce vpart over 512 threads (features)
    #pragma unroll
    for (int bb = 0; bb < 2; ++bb)
        #pragma unroll
        for (int n = 0; n < 30; ++n) {
            float v = vpart[bb][n];
            for (int s = 1; s < 64; s <<= 1) v += __shfl_xor(v, s);
            if (lane == 0) red[wv * 64 + bb * 30 + n] = v;
        }
    __syncthreads();
    if (tid < 60) {
        float s = 0.f;
        #pragma unroll
        for (int w2 = 0; w2 < 8; ++w2) s += red[w2 * 64 + tid];
        vl[tid] = s;
    }
    __syncthreads();
    if (tid < 60) {
        const int bb = tid / 30, n = tid - bb * 30;
        float z = bl[0];
        #pragma unroll
        for (int j = 0; j < 30; ++j) z = fmaf(Pl[bb * 900 + n * 30 + j], vl[bb * 30 + j], z);
        zl[tid] = fmaxf(z, 0.f);
    }
    __syncthreads();
    if (tid < 8) {
        const int bb = tid >> 2, c = tid & 3;
        float o = bc[c];
        #pragma unroll
        for (int n = 0; n < 30; ++n) o = fmaf(zl[bb * 30 + n], wc[c * 30 + n], o);
        out[(blk * 2 + bb) * 4 + c] = o;
    }
}

extern "C" void kernel_launch(void* const* d_in, const int* in_sizes, int n_in,
                              void* d_out, int out_size, void* d_ws, size_t ws_size,
                              hipStream_t stream) {
    const float* real  = (const float*)d_in[0];
    // d_in[1] = imag (unused by the reference)
    const float* graph = (const float*)d_in[2];
    const float* W1    = (const float*)d_in[3];
    const float* b1    = (const float*)d_in[4];
    const float* W2    = (const float*)d_in[5];
    const float* b2    = (const float*)d_in[6];
    const float* Wl    = (const float*)d_in[7];
    const float* bl    = (const float*)d_in[8];
    const float* Wc    = (const float*)d_in[9];
    const float* bc    = (const float*)d_in[10];
    float* out = (float*)d_out;
    char*  ws  = (char*)d_ws;

    float* Pws = (float*)(ws + P_OFF);
    f16*   w1t = (f16*)(ws + W1T_OFF);
    f16*   w2t = (f16*)(ws + W2T_OFF);

    k_prep<<<1536, 256, 0, stream>>>(W1, W2, w1t, w2t);
    k_prop<<<4096, 256, 0, stream>>>(graph, Pws);
    (void)hipFuncSetAttribute((const void*)k_main,
                              hipFuncAttributeMaxDynamicSharedMemorySize, SMEM_BYTES);
    k_main<<<2048, 512, SMEM_BYTES, stream>>>(real, w1t, w2t, b1, b2, Wl, bl, Wc, bc,
                                              Pws, out);
}

// Round 2
// 386.573 us; speedup vs baseline: 12.7068x; 12.7068x over previous
//
#include <hip/hip_runtime.h>
#include <hip/hip_bf16.h>

typedef _Float16 f16;
typedef _Float16 f16x8 __attribute__((ext_vector_type(8)));
typedef _Float16 f16x4 __attribute__((ext_vector_type(4)));
typedef float f32x4 __attribute__((ext_vector_type(4)));

// ---------------- ws layout (bytes) ----------------
#define P_OFF   0
#define W1T_OFF 14745600
#define W2T_OFF 15007744

// ---------------- k_prep: transpose + f32->f16 weights ----------------
__global__ __launch_bounds__(256) void k_prep(const float* __restrict__ W1,
                                              const float* __restrict__ W2,
                                              f16* __restrict__ w1t,
                                              f16* __restrict__ w2t) {
    long id = (long)blockIdx.x * 256 + threadIdx.x;   // 0 .. 393215
    if (id < 131072) {
        int f = (int)(id >> 8), k = (int)(id & 255);
        w1t[id] = (f16)W1[k * 512 + f];               // w1t[f][k], k=0..255
    } else {
        long i = id - 131072;
        int f = (int)(i >> 9), k = (int)(i & 511);
        w2t[i] = (f16)W2[k * 512 + f];                // w2t[f][k], k=0..511
    }
}

// ---------------- k_prop: per-batch P = alpha*sum 0.9^k S^k + 0.9^10 S^10 ----
__global__ __launch_bounds__(256) void k_prop(const float* __restrict__ graph,
                                              float* __restrict__ P) {
    __shared__ float Mt[900];
    __shared__ float Sm[900];
    __shared__ float Q[900];
    __shared__ float T[900];
    __shared__ float R[900];
    __shared__ float dinv[30];
    const int tid = threadIdx.x;
    const int b = blockIdx.x;
    const float* g = graph + (long)b * 4500;

    for (int e = tid; e < 900; e += 256) {
        float s = g[e];
        s += g[900 + e]; s += g[1800 + e]; s += g[2700 + e]; s += g[3600 + e];
        int i = e / 30, j = e - i * 30;
        float m = (s != 0.0f) ? 1.0f : 0.0f;
        Mt[e] = m + ((i == j) ? 1.0f : 0.0f);
    }
    __syncthreads();
    if (tid < 30) {
        float d = 0.f;
        for (int i = 0; i < 30; ++i) d += Mt[i * 30 + tid];
        dinv[tid] = 1.0f / sqrtf(d);
    }
    __syncthreads();
    for (int e = tid; e < 900; e += 256) {
        int i = e / 30, j = e - i * 30;
        float s = dinv[i] * Mt[j * 30 + i] * dinv[j];
        Sm[e] = s;
        Q[e] = s;
        R[e] = 0.1f * ((i == j) ? 1.0f : 0.0f);
    }
    __syncthreads();
    float c = 0.1f, g9 = 1.0f;
    for (int k = 1; k <= 9; ++k) {
        c *= 0.9f; g9 *= 0.9f;
        for (int e = tid; e < 900; e += 256) {
            int i = e / 30, j = e - i * 30;
            R[e] += c * Q[e];
            float acc = 0.f;
            #pragma unroll
            for (int t = 0; t < 30; ++t) acc += Sm[i * 30 + t] * Q[t * 30 + j];
            T[e] = acc;
        }
        __syncthreads();
        for (int e = tid; e < 900; e += 256) Q[e] = T[e];
        __syncthreads();
    }
    const float cf = g9 * 0.9f;
    for (int e = tid; e < 900; e += 256)
        P[(long)b * 900 + e] = R[e] + cf * Q[e];
}

// ---------------- k_main ----------------
// block = 2 batches (60 rows padded to 64), 512 threads = 8 waves (cols).
// LDS: one 64KB buffer aliased as As[64][256]f16 -> xl[64][512]f16 -> ut[512][64]f16
#define SMEM_BYTES 79424
#define XL_OFF   0
#define PF_OFF   65536   // Pf16 [2][32][32] f16 = 4096
#define PL_OFF   69632   // Pl   [2][900] f32   = 7200
#define RED_OFF  76832   // red  [8][64] f32    = 2048
#define VL_OFF   78880   // vl   [64] f32
#define ZL_OFF   79136   // zl   [64] f32

__global__ __launch_bounds__(512, 2) void k_main(
    const float* __restrict__ real, const f16* __restrict__ w1t,
    const f16* __restrict__ w2t, const float* __restrict__ b1,
    const float* __restrict__ b2, const float* __restrict__ wl,
    const float* __restrict__ bl, const float* __restrict__ wc,
    const float* __restrict__ bc, const float* __restrict__ Pws,
    float* __restrict__ out) {
    extern __shared__ char smem[];
    char*  buf = smem + XL_OFF;          // As / xl / ut alias
    f16*   Pf  = (f16*)(smem + PF_OFF);
    float* Pl  = (float*)(smem + PL_OFF);
    float* red = (float*)(smem + RED_OFF);
    float* vl  = (float*)(smem + VL_OFF);
    float* zl  = (float*)(smem + ZL_OFF);

    const int tid  = threadIdx.x;
    const int lane = tid & 63;
    const int wv   = tid >> 6;          // wave 0..7, owns cols wv*64..+63
    const int g    = lane >> 4;         // quad group 0..3
    const int lr   = lane & 15;
    const int blk  = blockIdx.x;        // 0..2047
    const long r0  = (long)blk * 60;

    // ---- stage A once: As[64][256] f16, swizzled rows (512B), rows>=60 zero ----
    #pragma unroll
    for (int s = 0; s < 4; ++s) {
        int id  = tid + s * 512;          // 0..2047
        int row = id >> 5;                // 0..63
        int c8  = id & 31;                // 8-float chunk
        float4 v0 = {0.f,0.f,0.f,0.f}, v1 = {0.f,0.f,0.f,0.f};
        if (row < 60) {
            const float* p = real + (r0 + row) * 256 + c8 * 8;
            v0 = *reinterpret_cast<const float4*>(p);
            v1 = *reinterpret_cast<const float4*>(p + 4);
        }
        f16x8 h;
        h[0]=(f16)v0.x; h[1]=(f16)v0.y; h[2]=(f16)v0.z; h[3]=(f16)v0.w;
        h[4]=(f16)v1.x; h[5]=(f16)v1.y; h[6]=(f16)v1.z; h[7]=(f16)v1.w;
        *reinterpret_cast<f16x8*>(buf + row * 512 + ((c8 * 16) ^ ((row & 7) << 4))) = h;
    }
    // ---- load P (f32) ----
    for (int e = tid; e < 1800; e += 512) Pl[e] = Pws[(long)blk * 1800 + e];
    __syncthreads();
    // ---- build Pf16 [2][32][32] (padded, zero outside 30x30) ----
    #pragma unroll
    for (int s = 0; s < 4; ++s) {
        int e = tid + s * 512;            // 0..2047
        int bb = e >> 10, idx = e & 1023, n = idx >> 5, k = idx & 31;
        float p = (n < 30 && k < 30) ? Pl[bb * 900 + n * 30 + k] : 0.f;
        Pf[e] = (f16)p;
    }

    f32x4 acc[4][4];
    #pragma unroll
    for (int mi = 0; mi < 4; ++mi)
        #pragma unroll
        for (int ni = 0; ni < 4; ++ni) { f32x4 z = {0.f,0.f,0.f,0.f}; acc[mi][ni] = z; }

    // ======== GEMM1: acc = A(real,f16) @ W1, K=256 — barrier-free ========
    for (int kc = 0; kc < 8; ++kc) {
        const int k0 = kc * 32;
        f16x8 bf[4], af[4];
        #pragma unroll
        for (int ni = 0; ni < 4; ++ni) {
            const int n = wv * 64 + ni * 16 + lr;
            bf[ni] = *reinterpret_cast<const f16x8*>(w1t + n * 256 + k0 + g * 8);
        }
        #pragma unroll
        for (int mi = 0; mi < 4; ++mi) {
            const int row = mi * 16 + lr;
            af[mi] = *reinterpret_cast<const f16x8*>(
                buf + row * 512 + (((k0 + g * 8) * 2) ^ ((row & 7) << 4)));
        }
        #pragma unroll
        for (int mi = 0; mi < 4; ++mi)
            #pragma unroll
            for (int ni = 0; ni < 4; ++ni)
                acc[mi][ni] = __builtin_amdgcn_mfma_f32_16x16x32_f16(af[mi], bf[ni], acc[mi][ni], 0, 0, 0);
    }
    __syncthreads();   // all As reads done; buf becomes xl[64][512]

    // ---- epilogue1: x = relu(acc + b1) -> xl (f16, row-swizzled 1024B rows) ----
    {
        float b1r[4];
        #pragma unroll
        for (int ni = 0; ni < 4; ++ni) b1r[ni] = b1[wv * 64 + ni * 16 + lr];
        #pragma unroll
        for (int mi = 0; mi < 4; ++mi)
            #pragma unroll
            for (int ni = 0; ni < 4; ++ni)
                #pragma unroll
                for (int j = 0; j < 4; ++j) {
                    const int row = mi * 16 + g * 4 + j;
                    const int col = wv * 64 + ni * 16 + lr;
                    float xv = fmaxf(acc[mi][ni][j] + b1r[ni], 0.f);
                    *reinterpret_cast<f16*>(buf + row * 1024 + ((col * 2) ^ ((row & 7) << 4))) = (f16)xv;
                }
    }
    #pragma unroll
    for (int mi = 0; mi < 4; ++mi)
        #pragma unroll
        for (int ni = 0; ni < 4; ++ni) { f32x4 z = {0.f,0.f,0.f,0.f}; acc[mi][ni] = z; }
    __syncthreads();   // xl visible to all waves

    // ======== GEMM2: acc = x @ W2, K=512 — barrier-free ========
    for (int kc = 0; kc < 16; ++kc) {
        const int k0 = kc * 32;
        f16x8 bf[4], af[4];
        #pragma unroll
        for (int ni = 0; ni < 4; ++ni) {
            const int n = wv * 64 + ni * 16 + lr;
            bf[ni] = *reinterpret_cast<const f16x8*>(w2t + n * 512 + k0 + g * 8);
        }
        #pragma unroll
        for (int mi = 0; mi < 4; ++mi) {
            const int row = mi * 16 + lr;
            af[mi] = *reinterpret_cast<const f16x8*>(
                buf + row * 1024 + (((k0 + g * 8) * 2) ^ ((row & 7) << 4)));
        }
        #pragma unroll
        for (int mi = 0; mi < 4; ++mi)
            #pragma unroll
            for (int ni = 0; ni < 4; ++ni)
                acc[mi][ni] = __builtin_amdgcn_mfma_f32_16x16x32_f16(af[mi], bf[ni], acc[mi][ni], 0, 0, 0);
    }
    __syncthreads();   // all xl reads done; buf becomes ut[512][64]

    // ---- epilogue2: write u^T: ut[feature][node'] f16 (128B rows, swizzled) ----
    // node' = node + (node>=30 ? 2 : 0)  => batch0 rows 0..29, batch1 rows 32..61
    #pragma unroll
    for (int mi = 0; mi < 4; ++mi)
        #pragma unroll
        for (int ni = 0; ni < 4; ++ni)
            #pragma unroll
            for (int j = 0; j < 4; ++j) {
                const int row = mi * 16 + g * 4 + j;     // node 0..63
                if (row < 60) {
                    const int rr  = row + (row >= 30 ? 2 : 0);
                    const int col = wv * 64 + ni * 16 + lr;
                    *reinterpret_cast<f16*>(buf + col * 128 + ((rr * 2) ^ ((col & 7) << 4)))
                        = (f16)acc[mi][ni][j];
                }
            }
    __syncthreads();

    // ======== phase5: Y^T = U^T @ P^T (MFMA), y=relu(+b2), v = y.wl ========
    {
        float b2r[4][4], wlr[4][4];
        #pragma unroll
        for (int mi = 0; mi < 4; ++mi)
            #pragma unroll
            for (int j = 0; j < 4; ++j) {
                const int f = wv * 64 + mi * 16 + g * 4 + j;
                b2r[mi][j] = b2[f];
                wlr[mi][j] = wl[f];
            }
        #pragma unroll
        for (int bb = 0; bb < 2; ++bb)
            #pragma unroll
            for (int ni = 0; ni < 2; ++ni) {
                // B-frag: B[k][n] = P[n][k]; lane holds n=ni*16+lr, k=g*8..+7
                f16x8 bfr = *reinterpret_cast<const f16x8*>(
                    (char*)Pf + bb * 2048 + (ni * 16 + lr) * 64 + g * 16);
                float vacc = 0.f;
                #pragma unroll
                for (int mi = 0; mi < 4; ++mi) {
                    const int f = wv * 64 + mi * 16 + lr;
                    f16x8 af = *reinterpret_cast<const f16x8*>(
                        buf + f * 128 + ((bb * 64 + g * 16) ^ ((f & 7) << 4)));
                    f32x4 d = {0.f,0.f,0.f,0.f};
                    d = __builtin_amdgcn_mfma_f32_16x16x32_f16(af, bfr, d, 0, 0, 0);
                    #pragma unroll
                    for (int j = 0; j < 4; ++j) {
                        float y = fmaxf(d[j] + b2r[mi][j], 0.f);
                        vacc = fmaf(y, wlr[mi][j], vacc);
                    }
                }
                vacc += __shfl_xor(vacc, 16);
                vacc += __shfl_xor(vacc, 32);
                if (lane < 16) red[wv * 64 + bb * 32 + ni * 16 + lr] = vacc;
            }
    }
    __syncthreads();
    if (tid < 64) {   // tid = bb*32 + n
        float s = 0.f;
        #pragma unroll
        for (int w = 0; w < 8; ++w) s += red[w * 64 + tid];
        vl[tid] = s;
    }
    __syncthreads();
    if (tid < 60) {
        const int bb = tid / 30, n = tid - bb * 30;
        float z = bl[0];
        #pragma unroll
        for (int j = 0; j < 30; ++j) z = fmaf(Pl[bb * 900 + n * 30 + j], vl[bb * 32 + j], z);
        zl[tid] = fmaxf(z, 0.f);
    }
    __syncthreads();
    if (tid < 8) {
        const int bb = tid >> 2, c = tid & 3;
        float o = bc[c];
        #pragma unroll
        for (int n = 0; n < 30; ++n) o = fmaf(zl[bb * 30 + n], wc[c * 30 + n], o);
        out[(blk * 2 + bb) * 4 + c] = o;
    }
}

extern "C" void kernel_launch(void* const* d_in, const int* in_sizes, int n_in,
                              void* d_out, int out_size, void* d_ws, size_t ws_size,
                              hipStream_t stream) {
    const float* real  = (const float*)d_in[0];
    const float* graph = (const float*)d_in[2];
    const float* W1    = (const float*)d_in[3];
    const float* b1    = (const float*)d_in[4];
    const float* W2    = (const float*)d_in[5];
    const float* b2    = (const float*)d_in[6];
    const float* Wl    = (const float*)d_in[7];
    const float* bl    = (const float*)d_in[8];
    const float* Wc    = (const float*)d_in[9];
    const float* bc    = (const float*)d_in[10];
    float* out = (float*)d_out;
    char*  ws  = (char*)d_ws;

    float* Pws = (float*)(ws + P_OFF);
    f16*   w1t = (f16*)(ws + W1T_OFF);
    f16*   w2t = (f16*)(ws + W2T_OFF);

    k_prep<<<1536, 256, 0, stream>>>(W1, W2, w1t, w2t);
    k_prop<<<4096, 256, 0, stream>>>(graph, Pws);
    (void)hipFuncSetAttribute((const void*)k_main,
                              hipFuncAttributeMaxDynamicSharedMemorySize, SMEM_BYTES);
    k_main<<<2048, 512, SMEM_BYTES, stream>>>(real, w1t, w2t, b1, b2, Wl, bl, Wc, bc,
                                              Pws, out);
}

// Round 3
// 245.038 us; speedup vs baseline: 20.0463x; 1.5776x over previous
//
#include <hip/hip_runtime.h>
#include <hip/hip_bf16.h>

typedef _Float16 f16;
typedef _Float16 f16x8 __attribute__((ext_vector_type(8)));
typedef _Float16 f16x4 __attribute__((ext_vector_type(4)));
typedef float f32x4 __attribute__((ext_vector_type(4)));

// ---------------- ws layout (bytes) ----------------
#define P_OFF   0
#define W1T_OFF 14745600
#define W2T_OFF 15007744

// ---------------- k_prep: transpose + f32->f16 weights ----------------
__global__ __launch_bounds__(256) void k_prep(const float* __restrict__ W1,
                                              const float* __restrict__ W2,
                                              f16* __restrict__ w1t,
                                              f16* __restrict__ w2t) {
    long id = (long)blockIdx.x * 256 + threadIdx.x;   // 0 .. 393215
    if (id < 131072) {
        int f = (int)(id >> 8), k = (int)(id & 255);
        w1t[id] = (f16)W1[k * 512 + f];               // w1t[f][k]
    } else {
        long i = id - 131072;
        int f = (int)(i >> 9), k = (int)(i & 511);
        w2t[i] = (f16)W2[k * 512 + f];                // w2t[f][k]
    }
}

// ---------------- k_prop: wave-per-batch MFMA polynomial build ----------------
// P = 0.1 * sum_{k=0..9} 0.9^k S^k + 0.9^10 S^10, S = Dinv Mt^T Dinv.
// S held as split-f16 (hi+lo) A-fragments; Q carried in D-registers; per hop
// Q is split-written to col-major LDS and re-read as B-fragments (3-product MFMA).
__global__ __launch_bounds__(256) void k_prop(const float* __restrict__ graph,
                                              float* __restrict__ P) {
    __shared__ float MtS[4][990];      // [r][c] padded 33
    __shared__ float dinvS[4][32];
    __shared__ f16 qhS[4][1024];       // col-major [col][row] 32x32
    __shared__ f16 qlS[4][1024];

    const int wv = threadIdx.x >> 6, lane = threadIdx.x & 63;
    const int lr = lane & 15, gq = lane >> 4;
    const long b = (long)blockIdx.x * 4 + wv;
    const float* g = graph + b * 4500;
    float* Mt = MtS[wv];
    float* dinv = dinvS[wv];
    f16* qh = qhS[wv];
    f16* ql = qlS[wv];

    for (int rep = 0; rep < 15; ++rep) {
        int e = rep * 64 + lane;
        if (e < 900) {
            float s = g[e] + g[900 + e] + g[1800 + e] + g[2700 + e] + g[3600 + e];
            int r = e / 30, c = e - r * 30;
            Mt[r * 33 + c] = ((s != 0.f) ? 1.f : 0.f) + ((r == c) ? 1.f : 0.f);
        }
    }
    __syncthreads();
    if (lane < 30) {
        float d = 0.f;
        #pragma unroll
        for (int r = 0; r < 30; ++r) d += Mt[r * 33 + lane];
        dinv[lane] = 1.0f / sqrtf(d);
    }
    __syncthreads();

    // S value (zero-padded to 32x32)
    auto Sval = [&](int i, int j) -> float {
        if (i >= 30 || j >= 30) return 0.f;
        return dinv[i] * Mt[j * 33 + i] * dinv[j];
    };

    // A-fragments of S, split hi/lo: row = mi*16+lr, k = gq*8+jj
    f16x8 sh[2], sl[2];
    #pragma unroll
    for (int mi = 0; mi < 2; ++mi)
        #pragma unroll
        for (int jj = 0; jj < 8; ++jj) {
            float v = Sval(mi * 16 + lr, gq * 8 + jj);
            f16 h = (f16)v;
            sh[mi][jj] = h;
            sl[mi][jj] = (f16)(v - (float)h);
        }

    // Q in D-layout registers: row = mi*16+gq*4+r, col = ni*16+lr
    f32x4 qd[2][2], racc[2][2];
    #pragma unroll
    for (int mi = 0; mi < 2; ++mi)
        #pragma unroll
        for (int ni = 0; ni < 2; ++ni)
            #pragma unroll
            for (int r = 0; r < 4; ++r) {
                int row = mi * 16 + gq * 4 + r, col = ni * 16 + lr;
                qd[mi][ni][r] = Sval(row, col);
                racc[mi][ni][r] = (row == col) ? 0.1f : 0.f;
            }

    float c = 0.1f;
    for (int k = 1; k <= 9; ++k) {
        c *= 0.9f;
        #pragma unroll
        for (int mi = 0; mi < 2; ++mi)
            #pragma unroll
            for (int ni = 0; ni < 2; ++ni) {
                racc[mi][ni] += c * qd[mi][ni];
                // split-store qd -> col-major LDS (b64 packed)
                f16x4 hh, ll;
                #pragma unroll
                for (int r = 0; r < 4; ++r) {
                    float v = qd[mi][ni][r];
                    f16 h = (f16)v;
                    hh[r] = h;
                    ll[r] = (f16)(v - (float)h);
                }
                const int col = ni * 16 + lr, rowb = mi * 16 + gq * 4;
                *reinterpret_cast<f16x4*>(qh + col * 32 + rowb) = hh;
                *reinterpret_cast<f16x4*>(ql + col * 32 + rowb) = ll;
            }
        __syncthreads();
        f16x8 bh[2], bl[2];
        #pragma unroll
        for (int ni = 0; ni < 2; ++ni) {
            const int col = ni * 16 + lr;
            bh[ni] = *reinterpret_cast<const f16x8*>(qh + col * 32 + gq * 8);
            bl[ni] = *reinterpret_cast<const f16x8*>(ql + col * 32 + gq * 8);
        }
        #pragma unroll
        for (int mi = 0; mi < 2; ++mi)
            #pragma unroll
            for (int ni = 0; ni < 2; ++ni) {
                f32x4 d = {0.f, 0.f, 0.f, 0.f};
                d = __builtin_amdgcn_mfma_f32_16x16x32_f16(sh[mi], bh[ni], d, 0, 0, 0);
                d = __builtin_amdgcn_mfma_f32_16x16x32_f16(sh[mi], bl[ni], d, 0, 0, 0);
                d = __builtin_amdgcn_mfma_f32_16x16x32_f16(sl[mi], bh[ni], d, 0, 0, 0);
                qd[mi][ni] = d;
            }
        __syncthreads();
    }
    const float cf = 0.3486784401f;   // 0.9^10
    #pragma unroll
    for (int mi = 0; mi < 2; ++mi)
        #pragma unroll
        for (int ni = 0; ni < 2; ++ni)
            #pragma unroll
            for (int r = 0; r < 4; ++r) {
                int row = mi * 16 + gq * 4 + r, col = ni * 16 + lr;
                if (row < 30 && col < 30)
                    P[b * 900 + row * 30 + col] = racc[mi][ni][r] + cf * qd[mi][ni][r];
            }
}

// ---------------- k_main ----------------
// block = 2 batches (rows 0-29 batch0, 32-61 batch1, 30/31/62/63 zero-pad),
// 512 threads = 8 waves (each owns 64 feature-cols).
#define SMEM_BYTES 78336
#define PF_OFF   65536   // Pf16 [2][32][32] f16 = 4096
#define B1L_OFF  69632   // [512] f32
#define B2L_OFF  71680   // [512] f32
#define WLL_OFF  73728   // [512] f32
#define RED_OFF  75776   // [8][64] f32 = 2048
#define VL_OFF   77824   // [64] f32
#define ZL_OFF   78080   // [64] f32

__global__ __launch_bounds__(512, 4) void k_main(
    const float* __restrict__ real, const f16* __restrict__ w1t,
    const f16* __restrict__ w2t, const float* __restrict__ b1,
    const float* __restrict__ b2, const float* __restrict__ wl,
    const float* __restrict__ bl, const float* __restrict__ wc,
    const float* __restrict__ bc, const float* __restrict__ Pws,
    float* __restrict__ out) {
    extern __shared__ char smem[];
    char*  buf = smem;                   // As[64][256] / xl[64][512] / ut[512][64]
    f16*   Pf  = (f16*)(smem + PF_OFF);
    float* b1l = (float*)(smem + B1L_OFF);
    float* b2l = (float*)(smem + B2L_OFF);
    float* wll = (float*)(smem + WLL_OFF);
    float* red = (float*)(smem + RED_OFF);
    float* vl  = (float*)(smem + VL_OFF);
    float* zl  = (float*)(smem + ZL_OFF);

    const int tid  = threadIdx.x;
    const int lane = tid & 63;
    const int wv   = tid >> 6;
    const int gq   = lane >> 4;
    const int lr   = lane & 15;
    const int blk  = blockIdx.x;
    const long r0  = (long)blk * 60;

    // ---- stage A once: As[64][256] f16, node-remapped, swizzled 512B rows ----
    #pragma unroll
    for (int s = 0; s < 4; ++s) {
        int id  = tid + s * 512;
        int row = id >> 5;
        int c8  = id & 31;
        int src = row - ((row >= 32) ? 2 : 0);
        bool valid = (row < 30) || (row >= 32 && row < 62);
        float4 v0 = {0.f,0.f,0.f,0.f}, v1 = {0.f,0.f,0.f,0.f};
        if (valid) {
            const float* p = real + (r0 + src) * 256 + c8 * 8;
            v0 = *reinterpret_cast<const float4*>(p);
            v1 = *reinterpret_cast<const float4*>(p + 4);
        }
        f16x8 h;
        h[0]=(f16)v0.x; h[1]=(f16)v0.y; h[2]=(f16)v0.z; h[3]=(f16)v0.w;
        h[4]=(f16)v1.x; h[5]=(f16)v1.y; h[6]=(f16)v1.z; h[7]=(f16)v1.w;
        *reinterpret_cast<f16x8*>(buf + row * 512 + ((c8 * 16) ^ ((row & 7) << 4))) = h;
    }
    // ---- Pf16 [2][32][32] zero-padded, from global P ----
    #pragma unroll
    for (int s = 0; s < 4; ++s) {
        int e = tid + s * 512;
        int bb = e >> 10, idx = e & 1023, n = idx >> 5, kk = idx & 31;
        float p = (n < 30 && kk < 30) ? Pws[(long)blk * 1800 + bb * 900 + n * 30 + kk] : 0.f;
        Pf[e] = (f16)p;
    }
    b1l[tid] = b1[tid];
    b2l[tid] = b2[tid];
    wll[tid] = wl[tid];

    f32x4 acc[4][4];
    #pragma unroll
    for (int mi = 0; mi < 4; ++mi)
        #pragma unroll
        for (int ni = 0; ni < 4; ++ni) { f32x4 z = {0.f,0.f,0.f,0.f}; acc[mi][ni] = z; }
    __syncthreads();

    // ======== GEMM1: acc = A @ W1, K=256 — barrier-free ========
    #pragma unroll 4
    for (int kc = 0; kc < 8; ++kc) {
        const int k0 = kc * 32;
        f16x8 bf[4], af[4];
        #pragma unroll
        for (int ni = 0; ni < 4; ++ni) {
            const int n = wv * 64 + ni * 16 + lr;
            bf[ni] = *reinterpret_cast<const f16x8*>(w1t + n * 256 + k0 + gq * 8);
        }
        #pragma unroll
        for (int mi = 0; mi < 4; ++mi) {
            const int row = mi * 16 + lr;
            af[mi] = *reinterpret_cast<const f16x8*>(
                buf + row * 512 + (((k0 + gq * 8) * 2) ^ ((row & 7) << 4)));
        }
        #pragma unroll
        for (int mi = 0; mi < 4; ++mi)
            #pragma unroll
            for (int ni = 0; ni < 4; ++ni)
                acc[mi][ni] = __builtin_amdgcn_mfma_f32_16x16x32_f16(af[mi], bf[ni], acc[mi][ni], 0, 0, 0);
    }
    __syncthreads();   // As reads done; buf becomes xl[64][512]

    // ---- epilogue1: x = relu(acc + b1) -> xl ----
    {
        float b1r[4];
        #pragma unroll
        for (int ni = 0; ni < 4; ++ni) b1r[ni] = b1l[wv * 64 + ni * 16 + lr];
        #pragma unroll
        for (int mi = 0; mi < 4; ++mi)
            #pragma unroll
            for (int ni = 0; ni < 4; ++ni)
                #pragma unroll
                for (int j = 0; j < 4; ++j) {
                    const int row = mi * 16 + gq * 4 + j;
                    const int col = wv * 64 + ni * 16 + lr;
                    float xv = fmaxf(acc[mi][ni][j] + b1r[ni], 0.f);
                    *reinterpret_cast<f16*>(buf + row * 1024 + ((col * 2) ^ ((row & 7) << 4))) = (f16)xv;
                }
    }
    #pragma unroll
    for (int mi = 0; mi < 4; ++mi)
        #pragma unroll
        for (int ni = 0; ni < 4; ++ni) { f32x4 z = {0.f,0.f,0.f,0.f}; acc[mi][ni] = z; }
    __syncthreads();

    // ======== GEMM2: acc = x @ W2, K=512 — barrier-free ========
    #pragma unroll 4
    for (int kc = 0; kc < 16; ++kc) {
        const int k0 = kc * 32;
        f16x8 bf[4], af[4];
        #pragma unroll
        for (int ni = 0; ni < 4; ++ni) {
            const int n = wv * 64 + ni * 16 + lr;
            bf[ni] = *reinterpret_cast<const f16x8*>(w2t + n * 512 + k0 + gq * 8);
        }
        #pragma unroll
        for (int mi = 0; mi < 4; ++mi) {
            const int row = mi * 16 + lr;
            af[mi] = *reinterpret_cast<const f16x8*>(
                buf + row * 1024 + (((k0 + gq * 8) * 2) ^ ((row & 7) << 4)));
        }
        #pragma unroll
        for (int mi = 0; mi < 4; ++mi)
            #pragma unroll
            for (int ni = 0; ni < 4; ++ni)
                acc[mi][ni] = __builtin_amdgcn_mfma_f32_16x16x32_f16(af[mi], bf[ni], acc[mi][ni], 0, 0, 0);
    }
    __syncthreads();   // xl reads done; buf becomes ut[512][64] (128B rows)

    // ---- epilogue2: u^T packed b64 writes: ut[feature][node] ----
    #pragma unroll
    for (int mi = 0; mi < 4; ++mi)
        #pragma unroll
        for (int ni = 0; ni < 4; ++ni) {
            const int col  = wv * 64 + ni * 16 + lr;    // feature
            const int rowb = mi * 16 + gq * 4;          // node quad base
            f16x4 h;
            #pragma unroll
            for (int r = 0; r < 4; ++r) h[r] = (f16)acc[mi][ni][r];
            *reinterpret_cast<f16x4*>(buf + col * 128 + ((rowb * 2) ^ ((col & 7) << 4))) = h;
        }
    __syncthreads();

    // ======== phase5: Y^T = U^T @ P^T (MFMA), y=relu(+b2), v = y.wl ========
    {
        float b2r[4][4], wlr[4][4];
        #pragma unroll
        for (int mi = 0; mi < 4; ++mi)
            #pragma unroll
            for (int j = 0; j < 4; ++j) {
                const int f = wv * 64 + mi * 16 + gq * 4 + j;
                b2r[mi][j] = b2l[f];
                wlr[mi][j] = wll[f];
            }
        #pragma unroll
        for (int bb = 0; bb < 2; ++bb)
            #pragma unroll
            for (int ni = 0; ni < 2; ++ni) {
                f16x8 bfr = *reinterpret_cast<const f16x8*>(
                    (char*)Pf + bb * 2048 + (ni * 16 + lr) * 64 + gq * 16);
                float vacc = 0.f;
                #pragma unroll
                for (int mi = 0; mi < 4; ++mi) {
                    const int f = wv * 64 + mi * 16 + lr;
                    f16x8 af = *reinterpret_cast<const f16x8*>(
                        buf + f * 128 + ((bb * 64 + gq * 16) ^ ((f & 7) << 4)));
                    f32x4 d = {0.f,0.f,0.f,0.f};
                    d = __builtin_amdgcn_mfma_f32_16x16x32_f16(af, bfr, d, 0, 0, 0);
                    #pragma unroll
                    for (int j = 0; j < 4; ++j) {
                        float y = fmaxf(d[j] + b2r[mi][j], 0.f);
                        vacc = fmaf(y, wlr[mi][j], vacc);
                    }
                }
                vacc += __shfl_xor(vacc, 16);
                vacc += __shfl_xor(vacc, 32);
                if (lane < 16) red[wv * 64 + bb * 32 + ni * 16 + lr] = vacc;
            }
    }
    __syncthreads();
    if (tid < 64) {
        float s = 0.f;
        #pragma unroll
        for (int w = 0; w < 8; ++w) s += red[w * 64 + tid];
        vl[tid] = s;
    }
    __syncthreads();
    if (tid < 60) {
        const int bb = tid / 30, n = tid - bb * 30;
        const float* Pr = Pws + (long)blk * 1800 + bb * 900 + n * 30;
        float z = bl[0];
        #pragma unroll
        for (int j = 0; j < 30; ++j) z = fmaf(Pr[j], vl[bb * 32 + j], z);
        zl[tid] = fmaxf(z, 0.f);
    }
    __syncthreads();
    if (tid < 8) {
        const int bb = tid >> 2, cc = tid & 3;
        float o = bc[cc];
        #pragma unroll
        for (int n = 0; n < 30; ++n) o = fmaf(zl[bb * 30 + n], wc[cc * 30 + n], o);
        out[(blk * 2 + bb) * 4 + cc] = o;
    }
}

extern "C" void kernel_launch(void* const* d_in, const int* in_sizes, int n_in,
                              void* d_out, int out_size, void* d_ws, size_t ws_size,
                              hipStream_t stream) {
    const float* real  = (const float*)d_in[0];
    const float* graph = (const float*)d_in[2];
    const float* W1    = (const float*)d_in[3];
    const float* b1    = (const float*)d_in[4];
    const float* W2    = (const float*)d_in[5];
    const float* b2    = (const float*)d_in[6];
    const float* Wl    = (const float*)d_in[7];
    const float* bl    = (const float*)d_in[8];
    const float* Wc    = (const float*)d_in[9];
    const float* bc    = (const float*)d_in[10];
    float* out = (float*)d_out;
    char*  ws  = (char*)d_ws;

    float* Pws = (float*)(ws + P_OFF);
    f16*   w1t = (f16*)(ws + W1T_OFF);
    f16*   w2t = (f16*)(ws + W2T_OFF);

    k_prep<<<1536, 256, 0, stream>>>(W1, W2, w1t, w2t);
    k_prop<<<1024, 256, 0, stream>>>(graph, Pws);
    (void)hipFuncSetAttribute((const void*)k_main,
                              hipFuncAttributeMaxDynamicSharedMemorySize, SMEM_BYTES);
    k_main<<<2048, 512, SMEM_BYTES, stream>>>(real, w1t, w2t, b1, b2, Wl, bl, Wc, bc,
                                              Pws, out);
}

// Round 4
// 185.781 us; speedup vs baseline: 26.4404x; 1.3190x over previous
//
#include <hip/hip_runtime.h>
#include <hip/hip_bf16.h>

typedef _Float16 f16;
typedef _Float16 f16x8 __attribute__((ext_vector_type(8)));
typedef _Float16 f16x4 __attribute__((ext_vector_type(4)));
typedef float f32x4 __attribute__((ext_vector_type(4)));

// ---------------- ws layout (bytes) ----------------
#define P_OFF   0
#define W1T_OFF 14745600
#define W2T_OFF 15007744

// ---------------- k_prep: transpose + f32->f16 weights ----------------
__global__ __launch_bounds__(256) void k_prep(const float* __restrict__ W1,
                                              const float* __restrict__ W2,
                                              f16* __restrict__ w1t,
                                              f16* __restrict__ w2t) {
    long id = (long)blockIdx.x * 256 + threadIdx.x;   // 0 .. 393215
    if (id < 131072) {
        int f = (int)(id >> 8), k = (int)(id & 255);
        w1t[id] = (f16)W1[k * 512 + f];               // w1t[f][k]
    } else {
        long i = id - 131072;
        int f = (int)(i >> 9), k = (int)(i & 511);
        w2t[i] = (f16)W2[k * 512 + f];                // w2t[f][k]
    }
}

// ---------------- k_prop: wave-per-batch MFMA polynomial build ----------------
__global__ __launch_bounds__(256) void k_prop(const float* __restrict__ graph,
                                              float* __restrict__ P) {
    __shared__ float MtS[4][990];
    __shared__ float dinvS[4][32];
    __shared__ f16 qhS[4][1024];
    __shared__ f16 qlS[4][1024];

    const int wv = threadIdx.x >> 6, lane = threadIdx.x & 63;
    const int lr = lane & 15, gq = lane >> 4;
    const long b = (long)blockIdx.x * 4 + wv;
    const float* g = graph + b * 4500;
    float* Mt = MtS[wv];
    float* dinv = dinvS[wv];
    f16* qh = qhS[wv];
    f16* ql = qlS[wv];

    for (int rep = 0; rep < 15; ++rep) {
        int e = rep * 64 + lane;
        if (e < 900) {
            float s = g[e] + g[900 + e] + g[1800 + e] + g[2700 + e] + g[3600 + e];
            int r = e / 30, c = e - r * 30;
            Mt[r * 33 + c] = ((s != 0.f) ? 1.f : 0.f) + ((r == c) ? 1.f : 0.f);
        }
    }
    __syncthreads();
    if (lane < 30) {
        float d = 0.f;
        #pragma unroll
        for (int r = 0; r < 30; ++r) d += Mt[r * 33 + lane];
        dinv[lane] = 1.0f / sqrtf(d);
    }
    __syncthreads();

    auto Sval = [&](int i, int j) -> float {
        if (i >= 30 || j >= 30) return 0.f;
        return dinv[i] * Mt[j * 33 + i] * dinv[j];
    };

    f16x8 sh[2], sl[2];
    #pragma unroll
    for (int mi = 0; mi < 2; ++mi)
        #pragma unroll
        for (int jj = 0; jj < 8; ++jj) {
            float v = Sval(mi * 16 + lr, gq * 8 + jj);
            f16 h = (f16)v;
            sh[mi][jj] = h;
            sl[mi][jj] = (f16)(v - (float)h);
        }

    f32x4 qd[2][2], racc[2][2];
    #pragma unroll
    for (int mi = 0; mi < 2; ++mi)
        #pragma unroll
        for (int ni = 0; ni < 2; ++ni)
            #pragma unroll
            for (int r = 0; r < 4; ++r) {
                int row = mi * 16 + gq * 4 + r, col = ni * 16 + lr;
                qd[mi][ni][r] = Sval(row, col);
                racc[mi][ni][r] = (row == col) ? 0.1f : 0.f;
            }

    float c = 0.1f;
    for (int k = 1; k <= 9; ++k) {
        c *= 0.9f;
        #pragma unroll
        for (int mi = 0; mi < 2; ++mi)
            #pragma unroll
            for (int ni = 0; ni < 2; ++ni) {
                racc[mi][ni] += c * qd[mi][ni];
                f16x4 hh, ll;
                #pragma unroll
                for (int r = 0; r < 4; ++r) {
                    float v = qd[mi][ni][r];
                    f16 h = (f16)v;
                    hh[r] = h;
                    ll[r] = (f16)(v - (float)h);
                }
                const int col = ni * 16 + lr, rowb = mi * 16 + gq * 4;
                *reinterpret_cast<f16x4*>(qh + col * 32 + rowb) = hh;
                *reinterpret_cast<f16x4*>(ql + col * 32 + rowb) = ll;
            }
        __syncthreads();
        f16x8 bh[2], bl[2];
        #pragma unroll
        for (int ni = 0; ni < 2; ++ni) {
            const int col = ni * 16 + lr;
            bh[ni] = *reinterpret_cast<const f16x8*>(qh + col * 32 + gq * 8);
            bl[ni] = *reinterpret_cast<const f16x8*>(ql + col * 32 + gq * 8);
        }
        #pragma unroll
        for (int mi = 0; mi < 2; ++mi)
            #pragma unroll
            for (int ni = 0; ni < 2; ++ni) {
                f32x4 d = {0.f, 0.f, 0.f, 0.f};
                d = __builtin_amdgcn_mfma_f32_16x16x32_f16(sh[mi], bh[ni], d, 0, 0, 0);
                d = __builtin_amdgcn_mfma_f32_16x16x32_f16(sh[mi], bl[ni], d, 0, 0, 0);
                d = __builtin_amdgcn_mfma_f32_16x16x32_f16(sl[mi], bh[ni], d, 0, 0, 0);
                qd[mi][ni] = d;
            }
        __syncthreads();
    }
    const float cf = 0.3486784401f;   // 0.9^10
    #pragma unroll
    for (int mi = 0; mi < 2; ++mi)
        #pragma unroll
        for (int ni = 0; ni < 2; ++ni)
            #pragma unroll
            for (int r = 0; r < 4; ++r) {
                int row = mi * 16 + gq * 4 + r, col = ni * 16 + lr;
                if (row < 30 && col < 30)
                    P[b * 900 + row * 30 + col] = racc[mi][ni][r] + cf * qd[mi][ni][r];
            }
}

// ---------------- k_main ----------------
// block = 4 batches (rows q*32+0..29 valid, q*32+{30,31} zero-pad), M=128.
// 512 threads = 8 waves; each wave owns 64 feature-cols, all 128 node rows.
// LDS buf alias: As[128][256]f16 (64K) -> xl[128][512]f16 (128K) -> ut[512][128]f16 (128K)
#define SMEM_BYTES 150496
#define PF_OFF   131072  // Pf [4][32][32] f16 = 8192
#define B1L_OFF  139264  // [512] f32
#define B2L_OFF  141312  // [512] f32
#define WLL_OFF  143360  // [512] f32
#define RED_OFF  145408  // [8][128] f32 = 4096
#define VL_OFF   149504  // [128] f32
#define ZL_OFF   150016  // [120] f32

__global__ __launch_bounds__(512, 2) void k_main(
    const float* __restrict__ real, const f16* __restrict__ w1t,
    const f16* __restrict__ w2t, const float* __restrict__ b1,
    const float* __restrict__ b2, const float* __restrict__ wl,
    const float* __restrict__ bl, const float* __restrict__ wc,
    const float* __restrict__ bc, const float* __restrict__ Pws,
    float* __restrict__ out) {
    extern __shared__ char smem[];
    char*  buf = smem;
    f16*   Pf  = (f16*)(smem + PF_OFF);
    float* b1l = (float*)(smem + B1L_OFF);
    float* b2l = (float*)(smem + B2L_OFF);
    float* wll = (float*)(smem + WLL_OFF);
    float* red = (float*)(smem + RED_OFF);
    float* vl  = (float*)(smem + VL_OFF);
    float* zl  = (float*)(smem + ZL_OFF);

    const int tid  = threadIdx.x;
    const int lane = tid & 63;
    const int wv   = tid >> 6;
    const int gq   = lane >> 4;
    const int lr   = lane & 15;
    const int blk  = blockIdx.x;         // 0..1023
    const long r0  = (long)blk * 120;

    // ---- stage As[128][256] f16 (swizzled 512B rows); pad rows -> 0 ----
    #pragma unroll
    for (int s = 0; s < 8; ++s) {
        int id  = tid + s * 512;          // 0..4095
        int row = id >> 5;                // 0..127
        int c8  = id & 31;
        int q = row >> 5, rr = row & 31;
        float4 v0 = {0.f,0.f,0.f,0.f}, v1 = {0.f,0.f,0.f,0.f};
        if (rr < 30) {
            const float* p = real + (r0 + q * 30 + rr) * 256 + c8 * 8;
            v0 = *reinterpret_cast<const float4*>(p);
            v1 = *reinterpret_cast<const float4*>(p + 4);
        }
        f16x8 h;
        h[0]=(f16)v0.x; h[1]=(f16)v0.y; h[2]=(f16)v0.z; h[3]=(f16)v0.w;
        h[4]=(f16)v1.x; h[5]=(f16)v1.y; h[6]=(f16)v1.z; h[7]=(f16)v1.w;
        *reinterpret_cast<f16x8*>(buf + row * 512 + ((c8 * 16) ^ ((row & 7) << 4))) = h;
    }
    // ---- Pf [4][32][32] f16, zero-padded ----
    #pragma unroll
    for (int s = 0; s < 8; ++s) {
        int e = tid + s * 512;            // 0..4095
        int bb = e >> 10, idx = e & 1023, n = idx >> 5, kk = idx & 31;
        float p = (n < 30 && kk < 30) ? Pws[((long)blk * 4 + bb) * 900 + n * 30 + kk] : 0.f;
        Pf[e] = (f16)p;
    }
    b1l[tid] = b1[tid];
    b2l[tid] = b2[tid];
    wll[tid] = wl[tid];

    f32x4 acc[4][8];   // GEMM1: [feat-frag][node-frag]; GEMM2 reuses as [ni][mi]
    #pragma unroll
    for (int a = 0; a < 4; ++a)
        #pragma unroll
        for (int b = 0; b < 8; ++b) { f32x4 z = {0.f,0.f,0.f,0.f}; acc[a][b] = z; }
    __syncthreads();

    // ======== GEMM1: x^T = W1^T @ A^T  (D[feat][node]), K=256 ========
    // A-frag from w1t (feat rows), B-frag from As (node cols). Double-buffered A.
    const f16* w1p = w1t + (wv * 64 + lr) * 256;
    f16x8 afA[4], afB[4];
    #pragma unroll
    for (int mi = 0; mi < 4; ++mi)
        afA[mi] = *reinterpret_cast<const f16x8*>(w1p + mi * 4096 + 0 * 32 + gq * 8);
    #pragma unroll
    for (int mi = 0; mi < 4; ++mi)
        afB[mi] = *reinterpret_cast<const f16x8*>(w1p + mi * 4096 + 1 * 32 + gq * 8);
    #pragma unroll
    for (int kc2 = 0; kc2 < 4; ++kc2) {
        {   // even kc
            const int kc = 2 * kc2;
            f16x8 bf[8];
            #pragma unroll
            for (int ni = 0; ni < 8; ++ni) {
                const int row = ni * 16 + lr;
                bf[ni] = *reinterpret_cast<const f16x8*>(
                    buf + row * 512 + (((kc * 32 + gq * 8) * 2) ^ ((row & 7) << 4)));
            }
            #pragma unroll
            for (int mi = 0; mi < 4; ++mi)
                #pragma unroll
                for (int ni = 0; ni < 8; ++ni)
                    acc[mi][ni] = __builtin_amdgcn_mfma_f32_16x16x32_f16(afA[mi], bf[ni], acc[mi][ni], 0, 0, 0);
            if (kc + 2 < 8)
                #pragma unroll
                for (int mi = 0; mi < 4; ++mi)
                    afA[mi] = *reinterpret_cast<const f16x8*>(w1p + mi * 4096 + (kc + 2) * 32 + gq * 8);
        }
        {   // odd kc
            const int kc = 2 * kc2 + 1;
            f16x8 bf[8];
            #pragma unroll
            for (int ni = 0; ni < 8; ++ni) {
                const int row = ni * 16 + lr;
                bf[ni] = *reinterpret_cast<const f16x8*>(
                    buf + row * 512 + (((kc * 32 + gq * 8) * 2) ^ ((row & 7) << 4)));
            }
            #pragma unroll
            for (int mi = 0; mi < 4; ++mi)
                #pragma unroll
                for (int ni = 0; ni < 8; ++ni)
                    acc[mi][ni] = __builtin_amdgcn_mfma_f32_16x16x32_f16(afB[mi], bf[ni], acc[mi][ni], 0, 0, 0);
            if (kc + 2 < 8)
                #pragma unroll
                for (int mi = 0; mi < 4; ++mi)
                    afB[mi] = *reinterpret_cast<const f16x8*>(w1p + mi * 4096 + (kc + 2) * 32 + gq * 8);
        }
    }
    __syncthreads();   // As reads done everywhere; buf -> xl[128][512]

    // ---- ep1: x = relu(x^T + b1) -> xl[node][feat], b64 writes ----
    #pragma unroll
    for (int mi = 0; mi < 4; ++mi) {
        const int featb = wv * 64 + mi * 16 + gq * 4;
        float b1v[4];
        #pragma unroll
        for (int j = 0; j < 4; ++j) b1v[j] = b1l[featb + j];
        #pragma unroll
        for (int ni = 0; ni < 8; ++ni) {
            const int node = ni * 16 + lr;
            f16x4 h;
            #pragma unroll
            for (int j = 0; j < 4; ++j)
                h[j] = (f16)fmaxf(acc[mi][ni][j] + b1v[j], 0.f);
            *reinterpret_cast<f16x4*>(
                buf + node * 1024 + ((featb * 2) ^ ((node & 7) << 4))) = h;
        }
    }
    #pragma unroll
    for (int a = 0; a < 4; ++a)
        #pragma unroll
        for (int b = 0; b < 8; ++b) { f32x4 z = {0.f,0.f,0.f,0.f}; acc[a][b] = z; }
    __syncthreads();

    // ======== GEMM2: u = x @ W2 (D[node][feat]), K=512 ========
    // A-frag from xl (node rows), B-frag from w2t (feat cols). Double-buffered B.
    const f16* w2p = w2t + (wv * 64 + lr) * 512;
    f16x8 bfA[4], bfB[4];
    #pragma unroll
    for (int ni = 0; ni < 4; ++ni)
        bfA[ni] = *reinterpret_cast<const f16x8*>(w2p + ni * 8192 + 0 * 32 + gq * 8);
    #pragma unroll
    for (int ni = 0; ni < 4; ++ni)
        bfB[ni] = *reinterpret_cast<const f16x8*>(w2p + ni * 8192 + 1 * 32 + gq * 8);
    #pragma unroll
    for (int kc2 = 0; kc2 < 8; ++kc2) {
        {   // even kc
            const int kc = 2 * kc2;
            f16x8 af[8];
            #pragma unroll
            for (int mi = 0; mi < 8; ++mi) {
                const int row = mi * 16 + lr;
                af[mi] = *reinterpret_cast<const f16x8*>(
                    buf + row * 1024 + (((kc * 32 + gq * 8) * 2) ^ ((row & 7) << 4)));
            }
            #pragma unroll
            for (int mi = 0; mi < 8; ++mi)
                #pragma unroll
                for (int ni = 0; ni < 4; ++ni)
                    acc[ni][mi] = __builtin_amdgcn_mfma_f32_16x16x32_f16(af[mi], bfA[ni], acc[ni][mi], 0, 0, 0);
            if (kc + 2 < 16)
                #pragma unroll
                for (int ni = 0; ni < 4; ++ni)
                    bfA[ni] = *reinterpret_cast<const f16x8*>(w2p + ni * 8192 + (kc + 2) * 32 + gq * 8);
        }
        {   // odd kc
            const int kc = 2 * kc2 + 1;
            f16x8 af[8];
            #pragma unroll
            for (int mi = 0; mi < 8; ++mi) {
                const int row = mi * 16 + lr;
                af[mi] = *reinterpret_cast<const f16x8*>(
                    buf + row * 1024 + (((kc * 32 + gq * 8) * 2) ^ ((row & 7) << 4)));
            }
            #pragma unroll
            for (int mi = 0; mi < 8; ++mi)
                #pragma unroll
                for (int ni = 0; ni < 4; ++ni)
                    acc[ni][mi] = __builtin_amdgcn_mfma_f32_16x16x32_f16(af[mi], bfB[ni], acc[ni][mi], 0, 0, 0);
            if (kc + 2 < 16)
                #pragma unroll
                for (int ni = 0; ni < 4; ++ni)
                    bfB[ni] = *reinterpret_cast<const f16x8*>(w2p + ni * 8192 + (kc + 2) * 32 + gq * 8);
        }
    }
    __syncthreads();   // xl reads done; buf -> ut[512][128]

    // ---- ep2: write u^T: ut[feat][node], b64 writes, swizzled 256B rows ----
    #pragma unroll
    for (int mi = 0; mi < 8; ++mi)
        #pragma unroll
        for (int ni = 0; ni < 4; ++ni) {
            const int feat  = wv * 64 + ni * 16 + lr;
            const int node0 = mi * 16 + gq * 4;
            f16x4 h;
            #pragma unroll
            for (int j = 0; j < 4; ++j) h[j] = (f16)acc[ni][mi][j];
            *reinterpret_cast<f16x4*>(
                buf + feat * 256 + ((node0 * 2) ^ ((feat & 7) << 4))) = h;
        }
    __syncthreads();

    // ======== phase5: Y^T = U^T @ P^T (per batch), y=relu(+b2), v=y.wl ========
    {
        f16x8 pb[4][2];
        #pragma unroll
        for (int bb = 0; bb < 4; ++bb)
            #pragma unroll
            for (int ni = 0; ni < 2; ++ni)
                pb[bb][ni] = *reinterpret_cast<const f16x8*>(
                    Pf + bb * 1024 + (ni * 16 + lr) * 32 + gq * 8);
        float vacc[4][2];
        #pragma unroll
        for (int bb = 0; bb < 4; ++bb)
            #pragma unroll
            for (int ni = 0; ni < 2; ++ni) vacc[bb][ni] = 0.f;
        #pragma unroll
        for (int mi = 0; mi < 4; ++mi) {
            const int featb = wv * 64 + mi * 16;
            float b2v[4], wlv[4];
            #pragma unroll
            for (int j = 0; j < 4; ++j) {
                b2v[j] = b2l[featb + gq * 4 + j];
                wlv[j] = wll[featb + gq * 4 + j];
            }
            f16x8 au[4];
            #pragma unroll
            for (int bb = 0; bb < 4; ++bb) {
                const int feat = featb + lr;
                au[bb] = *reinterpret_cast<const f16x8*>(
                    buf + feat * 256 + ((bb * 64 + gq * 16) ^ ((feat & 7) << 4)));
            }
            #pragma unroll
            for (int bb = 0; bb < 4; ++bb)
                #pragma unroll
                for (int ni = 0; ni < 2; ++ni) {
                    f32x4 d = {0.f,0.f,0.f,0.f};
                    d = __builtin_amdgcn_mfma_f32_16x16x32_f16(au[bb], pb[bb][ni], d, 0, 0, 0);
                    #pragma unroll
                    for (int j = 0; j < 4; ++j) {
                        float y = fmaxf(d[j] + b2v[j], 0.f);
                        vacc[bb][ni] = fmaf(y, wlv[j], vacc[bb][ni]);
                    }
                }
        }
        #pragma unroll
        for (int bb = 0; bb < 4; ++bb)
            #pragma unroll
            for (int ni = 0; ni < 2; ++ni) {
                float v = vacc[bb][ni];
                v += __shfl_xor(v, 16);
                v += __shfl_xor(v, 32);
                if (lane < 16) red[wv * 128 + bb * 32 + ni * 16 + lr] = v;
            }
    }
    __syncthreads();
    if (tid < 128) {
        float s = 0.f;
        #pragma unroll
        for (int w = 0; w < 8; ++w) s += red[w * 128 + tid];
        vl[tid] = s;
    }
    __syncthreads();
    if (tid < 120) {
        const int bb = tid / 30, n = tid - bb * 30;
        const float* Pr = Pws + ((long)blk * 4 + bb) * 900 + n * 30;
        float z = bl[0];
        #pragma unroll
        for (int j = 0; j < 30; ++j) z = fmaf(Pr[j], vl[bb * 32 + j], z);
        zl[tid] = fmaxf(z, 0.f);
    }
    __syncthreads();
    if (tid < 16) {
        const int bb = tid >> 2, cc = tid & 3;
        float o = bc[cc];
        #pragma unroll
        for (int n = 0; n < 30; ++n) o = fmaf(zl[bb * 30 + n], wc[cc * 30 + n], o);
        out[((long)blk * 4 + bb) * 4 + cc] = o;
    }
}

extern "C" void kernel_launch(void* const* d_in, const int* in_sizes, int n_in,
                              void* d_out, int out_size, void* d_ws, size_t ws_size,
                              hipStream_t stream) {
    const float* real  = (const float*)d_in[0];
    const float* graph = (const float*)d_in[2];
    const float* W1    = (const float*)d_in[3];
    const float* b1    = (const float*)d_in[4];
    const float* W2    = (const float*)d_in[5];
    const float* b2    = (const float*)d_in[6];
    const float* Wl    = (const float*)d_in[7];
    const float* bl    = (const float*)d_in[8];
    const float* Wc    = (const float*)d_in[9];
    const float* bc    = (const float*)d_in[10];
    float* out = (float*)d_out;
    char*  ws  = (char*)d_ws;

    float* Pws = (float*)(ws + P_OFF);
    f16*   w1t = (f16*)(ws + W1T_OFF);
    f16*   w2t = (f16*)(ws + W2T_OFF);

    k_prep<<<1536, 256, 0, stream>>>(W1, W2, w1t, w2t);
    k_prop<<<1024, 256, 0, stream>>>(graph, Pws);
    (void)hipFuncSetAttribute((const void*)k_main,
                              hipFuncAttributeMaxDynamicSharedMemorySize, SMEM_BYTES);
    k_main<<<1024, 512, SMEM_BYTES, stream>>>(real, w1t, w2t, b1, b2, Wl, bl, Wc, bc,
                                              Pws, out);
}